// Round 1
// baseline (3968.020 us; speedup 1.0000x reference)
//
#include <hip/hip_runtime.h>
#include <hip/hip_bf16.h>
#include <math.h>

#define D_MODEL 512
#define D_INNER 1024
#define D_STATE 16
#define DT_RANK 32
#define N_LAYERS 4
#define BB 8
#define TT 1024
#define ROWS (BB * TT)      // 8192
#define IN_DIM 32
#define ACT_DIM 4
#define TGT_DIM 32
#define ACT_EMB 128
#define FUSE_IN (D_MODEL + ACT_EMB)  // 640
#define NCH 16
#define CHL (TT / NCH)      // 64

__device__ __forceinline__ float silu_f(float x) { return x / (1.f + __expf(-x)); }

// ---------------- embed: s_emb | silu(a_emb) -> emb (ROWS x 640) ----------------
__global__ __launch_bounds__(256) void embed_k(
    const float* __restrict__ state, const float* __restrict__ act,
    const float* __restrict__ W_state, const float* __restrict__ b_state,
    const float* __restrict__ W_act, const float* __restrict__ b_act,
    float* __restrict__ emb)
{
    int idx = blockIdx.x * 256 + threadIdx.x;   // ROWS*FUSE_IN exact
    int r = idx / FUSE_IN;
    int c = idx - r * FUSE_IN;
    if (c < D_MODEL) {
        float acc = b_state[c];
        const float* sp = state + (size_t)r * IN_DIM;
        #pragma unroll
        for (int k = 0; k < IN_DIM; ++k) acc = fmaf(sp[k], W_state[k * D_MODEL + c], acc);
        emb[idx] = acc;
    } else {
        int cc = c - D_MODEL;
        float acc = b_act[cc];
        const float* ap = act + (size_t)r * ACT_DIM;
        #pragma unroll
        for (int k = 0; k < ACT_DIM; ++k) acc = fmaf(ap[k], W_act[k * ACT_EMB + cc], acc);
        emb[idx] = silu_f(acc);
    }
}

// ---------------- generic fp32 GEMM: C(M,N) = A(M,K)@B(K,N) [+bias][softplus][+=C] ----
// flags: 1 = add bias, 2 = softplus, 4 = residual add into existing C
#define BM 64
#define BN 64
#define BK 16
__global__ __launch_bounds__(256) void gemm_f32(
    const float* __restrict__ A, const float* __restrict__ B,
    const float* __restrict__ bias, float* __restrict__ C,
    int M, int N, int K, int lda, int ldb, int ldc, int flags)
{
    __shared__ __align__(16) float As[BK][BM + 4];
    __shared__ __align__(16) float Bs[BK][BN];
    const int tid = threadIdx.x;
    const int bm = blockIdx.x * BM;
    const int bn = blockIdx.y * BN;
    const int tx = tid & 15;
    const int ty = tid >> 4;
    float acc[4][4] = {};
    for (int k0 = 0; k0 < K; k0 += BK) {
        #pragma unroll
        for (int i = 0; i < 4; ++i) {
            int l = tid + 256 * i;
            int m = l >> 4, kk = l & 15;
            int gm = bm + m, gk = k0 + kk;
            As[kk][m] = (gm < M && gk < K) ? A[(size_t)gm * lda + gk] : 0.f;
        }
        #pragma unroll
        for (int i = 0; i < 4; ++i) {
            int l = tid + 256 * i;
            int kk = l >> 6, n = l & 63;
            int gk = k0 + kk, gn = bn + n;
            Bs[kk][n] = (gk < K && gn < N) ? B[(size_t)gk * ldb + gn] : 0.f;
        }
        __syncthreads();
        #pragma unroll
        for (int kk = 0; kk < BK; ++kk) {
            float4 av = *(const float4*)&As[kk][ty * 4];
            float4 bv = *(const float4*)&Bs[kk][tx * 4];
            float a[4] = {av.x, av.y, av.z, av.w};
            float b[4] = {bv.x, bv.y, bv.z, bv.w};
            #pragma unroll
            for (int i = 0; i < 4; ++i)
                #pragma unroll
                for (int j = 0; j < 4; ++j)
                    acc[i][j] = fmaf(a[i], b[j], acc[i][j]);
        }
        __syncthreads();
    }
    #pragma unroll
    for (int i = 0; i < 4; ++i) {
        int gm = bm + ty * 4 + i;
        if (gm >= M) continue;
        #pragma unroll
        for (int j = 0; j < 4; ++j) {
            int gn = bn + tx * 4 + j;
            if (gn >= N) continue;
            float v = acc[i][j];
            if (flags & 1) v += bias[gn];
            if (flags & 2) v = (v > 20.f) ? v : log1pf(__expf(v));
            size_t o = (size_t)gm * ldc + gn;
            if (flags & 4) v += C[o];
            C[o] = v;
        }
    }
}

// ---------------- rmsnorm over 512, optional silu ----------------
__global__ __launch_bounds__(256) void rmsnorm_k(
    const float* __restrict__ in, const float* __restrict__ w,
    float* __restrict__ out, int flags)
{
    int row = blockIdx.x;
    int tid = threadIdx.x;
    const float* ip = in + (size_t)row * D_MODEL;
    float v0 = ip[tid], v1 = ip[tid + 256];
    float ss = v0 * v0 + v1 * v1;
    #pragma unroll
    for (int off = 32; off >= 1; off >>= 1) ss += __shfl_xor(ss, off, 64);
    __shared__ float red[4];
    if ((tid & 63) == 0) red[tid >> 6] = ss;
    __syncthreads();
    float tot = red[0] + red[1] + red[2] + red[3];
    float sc = rsqrtf(tot * (1.f / D_MODEL) + 1e-6f);
    float o0 = v0 * sc * w[tid];
    float o1 = v1 * sc * w[tid + 256];
    if (flags & 1) { o0 = silu_f(o0); o1 = silu_f(o1); }
    float* op = out + (size_t)row * D_MODEL;
    op[tid] = o0; op[tid + 256] = o1;
}

// ---------------- causal depthwise conv (k=4) + bias + silu ----------------
// reads xz lower half (ld 2048), writes xc (ld 1024)
__global__ __launch_bounds__(256) void conv_silu_k(
    const float* __restrict__ xz, const float* __restrict__ cw,
    const float* __restrict__ cb, float* __restrict__ xc)
{
    int idx = blockIdx.x * 256 + threadIdx.x;   // ROWS*D_INNER exact
    int d = idx & (D_INNER - 1);
    int row = idx >> 10;
    int t = row & (TT - 1);
    float4 w = *(const float4*)(cw + (size_t)d * 4);
    float acc = cb[d];
    if (t >= 3) {
        const float* base = xz + (size_t)(row - 3) * (2 * D_INNER) + d;
        acc = fmaf(base[0],        w.x, acc);
        acc = fmaf(base[2048],     w.y, acc);
        acc = fmaf(base[4096],     w.z, acc);
        acc = fmaf(base[6144],     w.w, acc);
    } else {
        float wv[4] = {w.x, w.y, w.z, w.w};
        int bstart = row - t;
        #pragma unroll
        for (int j = 0; j < 4; ++j) {
            int ts = t + j - 3;
            if (ts >= 0) acc = fmaf(xz[(size_t)(bstart + ts) * (2 * D_INNER) + d], wv[j], acc);
        }
    }
    xc[idx] = silu_f(acc);
}

// ---------------- chunked selective scan ----------------
// layout of hf/pf/hin: (b, chunk, d, s)
__global__ __launch_bounds__(256) void scan_pass1_k(
    const float* __restrict__ dt, const float* __restrict__ xc,
    const float* __restrict__ xdbl, const float* __restrict__ A_log,
    float* __restrict__ hf, float* __restrict__ pf)
{
    int tid = threadIdx.x;
    int s = tid & 15, dl = tid >> 4;
    int d = blockIdx.x * 16 + dl;
    int c = blockIdx.y;
    int b = blockIdx.z;
    float Av = -__expf(A_log[d * 16 + s]);
    float h = 0.f, P = 1.f;
    int row0 = b * TT + c * CHL;
    for (int t = 0; t < CHL; ++t) {
        size_t row = (size_t)(row0 + t);
        float dtv = dt[row * D_INNER + d];
        float xv  = xc[row * D_INNER + d];
        float Bv  = xdbl[row * 64 + DT_RANK + s];
        float dA  = __expf(dtv * Av);
        h = fmaf(dA, h, dtv * xv * Bv);
        P *= dA;
    }
    size_t o = ((((size_t)b * NCH + c) * D_INNER) + d) * 16 + s;
    hf[o] = h; pf[o] = P;
}

__global__ __launch_bounds__(256) void scan_combine_k(
    const float* __restrict__ hf, const float* __restrict__ pf,
    float* __restrict__ hin)
{
    int idx = blockIdx.x * 256 + threadIdx.x;   // BB*D_INNER*16 exact
    int b = idx >> 14;
    int rest = idx & 16383;                     // d*16+s
    float h = 0.f;
    for (int c = 0; c < NCH; ++c) {
        size_t o = (((size_t)b * NCH + c) * (D_INNER * 16)) + rest;
        hin[o] = h;
        h = fmaf(pf[o], h, hf[o]);
    }
}

__global__ __launch_bounds__(256) void scan_pass2_k(
    const float* __restrict__ dt, const float* __restrict__ xc,
    const float* __restrict__ xdbl, const float* __restrict__ A_log,
    const float* __restrict__ Dp, const float* __restrict__ hin,
    float* __restrict__ y)   // y written at row*2048+d (xz lower half)
{
    int tid = threadIdx.x;
    int s = tid & 15, dl = tid >> 4;
    int d = blockIdx.x * 16 + dl;
    int c = blockIdx.y;
    int b = blockIdx.z;
    float Av = -__expf(A_log[d * 16 + s]);
    float Dv = Dp[d];
    size_t ho = ((((size_t)b * NCH + c) * D_INNER) + d) * 16 + s;
    float h = hin[ho];
    int row0 = b * TT + c * CHL;
    for (int t = 0; t < CHL; ++t) {
        size_t row = (size_t)(row0 + t);
        float dtv = dt[row * D_INNER + d];
        float xv  = xc[row * D_INNER + d];
        float Bv  = xdbl[row * 64 + DT_RANK + s];
        float Cv  = xdbl[row * 64 + DT_RANK + D_STATE + s];
        float dA  = __expf(dtv * Av);
        h = fmaf(dA, h, dtv * xv * Bv);
        float p = h * Cv;
        p += __shfl_xor(p, 1);
        p += __shfl_xor(p, 2);
        p += __shfl_xor(p, 4);
        p += __shfl_xor(p, 8);
        if (s == 0) y[row * (2 * D_INNER) + d] = fmaf(xv, Dv, p);
    }
}

// ---------------- u = y * silu(z) ----------------
__global__ __launch_bounds__(256) void ymulz_k(const float* __restrict__ xz, float* __restrict__ u)
{
    int idx = blockIdx.x * 256 + threadIdx.x;   // ROWS*D_INNER exact
    int d = idx & (D_INNER - 1);
    size_t row = (size_t)(idx >> 10);
    float yv = xz[row * (2 * D_INNER) + d];
    float zv = xz[row * (2 * D_INNER) + D_INNER + d];
    u[idx] = yv * silu_f(zv);
}

__global__ __launch_bounds__(256) void copy_k(const float* __restrict__ src, float* __restrict__ dst, int n)
{
    int idx = blockIdx.x * 256 + threadIdx.x;
    if (idx < n) dst[idx] = src[idx];
}

extern "C" void kernel_launch(void* const* d_in, const int* in_sizes, int n_in,
                              void* d_out, int out_size, void* d_ws, size_t ws_size,
                              hipStream_t stream)
{
    const float* state   = (const float*)d_in[0];
    const float* pact    = (const float*)d_in[1];
    const float* W_state = (const float*)d_in[2];
    const float* b_state = (const float*)d_in[3];
    const float* W_act   = (const float*)d_in[4];
    const float* b_act   = (const float*)d_in[5];
    const float* W_fuse  = (const float*)d_in[6];
    const float* b_fuse  = (const float*)d_in[7];
    const float* g_fuse  = (const float*)d_in[8];
    const float* norm_w  = (const float*)d_in[9];
    const float* W_in    = (const float*)d_in[10];
    const float* conv_w  = (const float*)d_in[11];
    const float* conv_b  = (const float*)d_in[12];
    const float* W_x     = (const float*)d_in[13];
    const float* W_dt    = (const float*)d_in[14];
    const float* b_dt    = (const float*)d_in[15];
    const float* A_log   = (const float*)d_in[16];
    const float* Dp      = (const float*)d_in[17];
    const float* W_out   = (const float*)d_in[18];
    const float* W_head  = (const float*)d_in[19];
    const float* b_head  = (const float*)d_in[20];

    float* ws   = (float*)d_ws;
    float* X    = ws;                 // 8192*512
    float* XNDT = ws + 4194304;       // 8192*1024 (embed 640-wide / norm 512-wide / dt 1024-wide)
    float* XZ   = ws + 12582912;      // 8192*2048
    float* XC   = ws + 29360128;      // 8192*1024
    float* XDBL = ws + 37748736;      // 8192*64
    float* HF   = ws + 38273024;      // 8*16*1024*16
    float* PF   = ws + 40370176;
    float* HIN  = ws + 42467328;      // end = 44564480 floats (~170 MB)

    dim3 b256(256);

    embed_k<<<ROWS * FUSE_IN / 256, b256, 0, stream>>>(state, pact, W_state, b_state, W_act, b_act, XNDT);
    gemm_f32<<<dim3(128, 8), b256, 0, stream>>>(XNDT, W_fuse, b_fuse, X, ROWS, D_MODEL, FUSE_IN, FUSE_IN, D_MODEL, D_MODEL, 1);
    rmsnorm_k<<<ROWS, b256, 0, stream>>>(X, g_fuse, X, 1);

    for (int L = 0; L < N_LAYERS; ++L) {
        const float* Wi  = W_in  + (size_t)L * D_MODEL * (2 * D_INNER);
        const float* cw  = conv_w + (size_t)L * D_INNER * 4;
        const float* cb  = conv_b + (size_t)L * D_INNER;
        const float* Wx  = W_x   + (size_t)L * D_INNER * 64;
        const float* Wd  = W_dt  + (size_t)L * DT_RANK * D_INNER;
        const float* bd  = b_dt  + (size_t)L * D_INNER;
        const float* Al  = A_log + (size_t)L * D_INNER * D_STATE;
        const float* Dpl = Dp    + (size_t)L * D_INNER;
        const float* Wo  = W_out + (size_t)L * D_INNER * D_MODEL;

        rmsnorm_k<<<ROWS, b256, 0, stream>>>(X, norm_w + L * D_MODEL, XNDT, 0);
        gemm_f32<<<dim3(128, 32), b256, 0, stream>>>(XNDT, Wi, nullptr, XZ, ROWS, 2 * D_INNER, D_MODEL, D_MODEL, 2 * D_INNER, 2 * D_INNER, 0);
        conv_silu_k<<<ROWS * D_INNER / 256, b256, 0, stream>>>(XZ, cw, cb, XC);
        gemm_f32<<<dim3(128, 1), b256, 0, stream>>>(XC, Wx, nullptr, XDBL, ROWS, 64, D_INNER, D_INNER, 64, 64, 0);
        gemm_f32<<<dim3(128, 16), b256, 0, stream>>>(XDBL, Wd, bd, XNDT, ROWS, D_INNER, DT_RANK, 64, D_INNER, D_INNER, 3);
        scan_pass1_k<<<dim3(64, NCH, BB), b256, 0, stream>>>(XNDT, XC, XDBL, Al, HF, PF);
        scan_combine_k<<<BB * D_INNER * 16 / 256, b256, 0, stream>>>(HF, PF, HIN);
        scan_pass2_k<<<dim3(64, NCH, BB), b256, 0, stream>>>(XNDT, XC, XDBL, Al, Dpl, HIN, XZ);
        ymulz_k<<<ROWS * D_INNER / 256, b256, 0, stream>>>(XZ, XC);
        gemm_f32<<<dim3(128, 8), b256, 0, stream>>>(XC, Wo, nullptr, X, ROWS, D_MODEL, D_INNER, D_INNER, D_MODEL, D_MODEL, 4);
    }

    gemm_f32<<<dim3(128, 1), b256, 0, stream>>>(X, W_head, b_head, (float*)d_out, ROWS, TGT_DIM, D_MODEL, D_MODEL, TGT_DIM, TGT_DIM, 1);
    copy_k<<<ROWS * D_MODEL / 256, b256, 0, stream>>>(X, (float*)d_out + ROWS * TGT_DIM, ROWS * D_MODEL);
}

// Round 2
// 2240.510 us; speedup vs baseline: 1.7710x; 1.7710x over previous
//
#include <hip/hip_runtime.h>
#include <hip/hip_bf16.h>
#include <math.h>

#define D_MODEL 512
#define D_INNER 1024
#define D_STATE 16
#define DT_RANK 32
#define N_LAYERS 4
#define BB 8
#define TT 1024
#define ROWS (BB * TT)      // 8192
#define IN_DIM 32
#define ACT_DIM 4
#define TGT_DIM 32
#define ACT_EMB 128
#define FUSE_IN (D_MODEL + ACT_EMB)  // 640
#define NCH 16
#define CHL (TT / NCH)      // 64

typedef __attribute__((ext_vector_type(8))) short short8;   // 8 bf16 (4 VGPRs)
typedef __attribute__((ext_vector_type(4))) float f32x4;

__device__ __forceinline__ float silu_f(float x) { return x / (1.f + __expf(-x)); }

#define GL2LDS(g, l) __builtin_amdgcn_global_load_lds( \
    (const __attribute__((address_space(1))) void*)(g), \
    (__attribute__((address_space(3))) void*)(l), 16, 0, 0)

// ---------------- transpose+cast weights: in (K,N) fp32 -> out (N,K) bf16 ---------
// K,N multiples of 64. grid: (N/64, K/64, layers)
__global__ __launch_bounds__(256) void transcast_k(
    const float* __restrict__ in, __hip_bfloat16* __restrict__ out, int K, int N)
{
    __shared__ float t[64][65];
    size_t zoff = (size_t)blockIdx.z * K * N;
    in += zoff; out += zoff;
    int k0 = blockIdx.y * 64, n0 = blockIdx.x * 64;
    int ln = threadIdx.x & 63, gr = threadIdx.x >> 6;
    #pragma unroll
    for (int i = 0; i < 16; ++i) {
        int kr = gr + i * 4;
        t[kr][ln] = in[(size_t)(k0 + kr) * N + n0 + ln];
    }
    __syncthreads();
    #pragma unroll
    for (int i = 0; i < 16; ++i) {
        int nr = gr + i * 4;
        out[(size_t)(n0 + nr) * K + k0 + ln] = __float2bfloat16(t[ln][nr]);
    }
}

// ---------------- embed: s_emb | silu(a_emb) -> emb bf16 (ROWS x 640) ----------------
__global__ __launch_bounds__(256) void embed_k(
    const float* __restrict__ state, const float* __restrict__ act,
    const float* __restrict__ W_state, const float* __restrict__ b_state,
    const float* __restrict__ W_act, const float* __restrict__ b_act,
    __hip_bfloat16* __restrict__ emb)
{
    int idx = blockIdx.x * 256 + threadIdx.x;   // ROWS*FUSE_IN exact
    int r = idx / FUSE_IN;
    int c = idx - r * FUSE_IN;
    float acc;
    if (c < D_MODEL) {
        acc = b_state[c];
        const float* sp = state + (size_t)r * IN_DIM;
        #pragma unroll
        for (int k = 0; k < IN_DIM; ++k) acc = fmaf(sp[k], W_state[k * D_MODEL + c], acc);
    } else {
        int cc = c - D_MODEL;
        acc = b_act[cc];
        const float* ap = act + (size_t)r * ACT_DIM;
        #pragma unroll
        for (int k = 0; k < ACT_DIM; ++k) acc = fmaf(ap[k], W_act[k * ACT_EMB + cc], acc);
        acc = silu_f(acc);
    }
    emb[idx] = __float2bfloat16(acc);
}

// ---------------- MFMA bf16 GEMM: C(M,N) fp32 = A(M,K)bf16 @ B^T(N,K)bf16 ----------
// BM=128, BN=128, BK=64; 256 threads = 4 waves, each wave 64x64.
// flags: 1 = add bias, 4 = residual add into existing C.
// M%128==0, N%128==0, K%64==0 required.
__global__ __launch_bounds__(256) void gemm_bf16(
    const __hip_bfloat16* __restrict__ A, const __hip_bfloat16* __restrict__ B,
    const float* __restrict__ bias, float* __restrict__ C,
    int M, int N, int K, int lda, int ldb, int ldc, int flags)
{
    __shared__ __hip_bfloat16 As[128 * 64];
    __shared__ __hip_bfloat16 Bs[128 * 64];
    const int tid  = threadIdx.x;
    const int wave = tid >> 6;
    const int lane = tid & 63;
    const size_t bm = (size_t)blockIdx.x * 128;
    const size_t bn = (size_t)blockIdx.y * 128;

    // staging geometry: chunk c2 = r*4+wave (0..15), row = c2*8 + lane/8,
    // LDS k-block = lane&7, global k-block = (lane&7) ^ (lane>>3)   [XOR swizzle]
    const int srow  = (lane >> 3);          // 0..7 within chunk
    const int gkblk = (lane & 7) ^ (lane >> 3);
    const int wr = wave >> 1, wc = wave & 1;
    const int mbase = wr * 64 + (lane & 15);
    const int nbase = wc * 64 + (lane & 15);
    const int quad  = lane >> 4;            // 0..3
    const int swz   = lane & 7;             // frag-read swizzle (= m&7 = n&7)

    f32x4 acc[4][4] = {};

    for (int k0 = 0; k0 < K; k0 += 64) {
        #pragma unroll
        for (int r = 0; r < 4; ++r) {
            int c2 = r * 4 + wave;
            int row = c2 * 8 + srow;
            const __hip_bfloat16* ga = A + (bm + row) * lda + k0 + gkblk * 8;
            GL2LDS(ga, As + (size_t)c2 * 512);
            const __hip_bfloat16* gb = B + (bn + row) * ldb + k0 + gkblk * 8;
            GL2LDS(gb, Bs + (size_t)c2 * 512);
        }
        __syncthreads();
        #pragma unroll
        for (int kk = 0; kk < 2; ++kk) {
            int kblk = kk * 4 + quad;
            int p = (kblk ^ swz) * 8;
            short8 af[4], bf[4];
            #pragma unroll
            for (int mi = 0; mi < 4; ++mi)
                af[mi] = *reinterpret_cast<const short8*>(&As[(mbase + mi * 16) * 64 + p]);
            #pragma unroll
            for (int ni = 0; ni < 4; ++ni)
                bf[ni] = *reinterpret_cast<const short8*>(&Bs[(nbase + ni * 16) * 64 + p]);
            #pragma unroll
            for (int mi = 0; mi < 4; ++mi)
                #pragma unroll
                for (int ni = 0; ni < 4; ++ni)
                    acc[mi][ni] = __builtin_amdgcn_mfma_f32_16x16x32_bf16(
                        af[mi], bf[ni], acc[mi][ni], 0, 0, 0);
        }
        __syncthreads();
    }

    #pragma unroll
    for (int ni = 0; ni < 4; ++ni) {
        int gn = (int)bn + wc * 64 + ni * 16 + (lane & 15);
        float bv = (flags & 1) ? bias[gn] : 0.f;
        #pragma unroll
        for (int mi = 0; mi < 4; ++mi) {
            #pragma unroll
            for (int r = 0; r < 4; ++r) {
                size_t gm = bm + wr * 64 + mi * 16 + quad * 4 + r;
                float v = acc[mi][ni][r] + bv;
                size_t o = gm * ldc + gn;
                if (flags & 4) v += C[o];
                C[o] = v;
            }
        }
    }
}

// ---------------- generic fp32 GEMM (small shapes): flags 1=bias,2=softplus,4=residual
#define BM 64
#define BN 64
#define BK 16
__global__ __launch_bounds__(256) void gemm_f32(
    const float* __restrict__ A, const float* __restrict__ B,
    const float* __restrict__ bias, float* __restrict__ C,
    int M, int N, int K, int lda, int ldb, int ldc, int flags)
{
    __shared__ __align__(16) float As[BK][BM + 4];
    __shared__ __align__(16) float Bs[BK][BN];
    const int tid = threadIdx.x;
    const int bm = blockIdx.x * BM;
    const int bn = blockIdx.y * BN;
    const int tx = tid & 15;
    const int ty = tid >> 4;
    float acc[4][4] = {};
    for (int k0 = 0; k0 < K; k0 += BK) {
        #pragma unroll
        for (int i = 0; i < 4; ++i) {
            int l = tid + 256 * i;
            int m = l >> 4, kk = l & 15;
            int gm = bm + m, gk = k0 + kk;
            As[kk][m] = (gm < M && gk < K) ? A[(size_t)gm * lda + gk] : 0.f;
        }
        #pragma unroll
        for (int i = 0; i < 4; ++i) {
            int l = tid + 256 * i;
            int kk = l >> 6, n = l & 63;
            int gk = k0 + kk, gn = bn + n;
            Bs[kk][n] = (gk < K && gn < N) ? B[(size_t)gk * ldb + gn] : 0.f;
        }
        __syncthreads();
        #pragma unroll
        for (int kk = 0; kk < BK; ++kk) {
            float4 av = *(const float4*)&As[kk][ty * 4];
            float4 bv = *(const float4*)&Bs[kk][tx * 4];
            float a[4] = {av.x, av.y, av.z, av.w};
            float b[4] = {bv.x, bv.y, bv.z, bv.w};
            #pragma unroll
            for (int i = 0; i < 4; ++i)
                #pragma unroll
                for (int j = 0; j < 4; ++j)
                    acc[i][j] = fmaf(a[i], b[j], acc[i][j]);
        }
        __syncthreads();
    }
    #pragma unroll
    for (int i = 0; i < 4; ++i) {
        int gm = bm + ty * 4 + i;
        if (gm >= M) continue;
        #pragma unroll
        for (int j = 0; j < 4; ++j) {
            int gn = bn + tx * 4 + j;
            if (gn >= N) continue;
            float v = acc[i][j];
            if (flags & 1) v += bias[gn];
            if (flags & 2) v = (v > 20.f) ? v : log1pf(__expf(v));
            size_t o = (size_t)gm * ldc + gn;
            if (flags & 4) v += C[o];
            C[o] = v;
        }
    }
}

// ---------------- rmsnorm over 512; flags: 1 = silu, 2 = bf16 output ----------------
__global__ __launch_bounds__(256) void rmsnorm_k(
    const float* __restrict__ in, const float* __restrict__ w,
    void* __restrict__ outp, int flags)
{
    int row = blockIdx.x;
    int tid = threadIdx.x;
    const float* ip = in + (size_t)row * D_MODEL;
    float v0 = ip[tid], v1 = ip[tid + 256];
    float ss = v0 * v0 + v1 * v1;
    #pragma unroll
    for (int off = 32; off >= 1; off >>= 1) ss += __shfl_xor(ss, off, 64);
    __shared__ float red[4];
    if ((tid & 63) == 0) red[tid >> 6] = ss;
    __syncthreads();
    float tot = red[0] + red[1] + red[2] + red[3];
    float sc = rsqrtf(tot * (1.f / D_MODEL) + 1e-6f);
    float o0 = v0 * sc * w[tid];
    float o1 = v1 * sc * w[tid + 256];
    if (flags & 1) { o0 = silu_f(o0); o1 = silu_f(o1); }
    if (flags & 2) {
        __hip_bfloat16* op = (__hip_bfloat16*)outp + (size_t)row * D_MODEL;
        op[tid] = __float2bfloat16(o0); op[tid + 256] = __float2bfloat16(o1);
    } else {
        float* op = (float*)outp + (size_t)row * D_MODEL;
        op[tid] = o0; op[tid + 256] = o1;
    }
}

// ---------------- causal depthwise conv (k=4) + bias + silu ----------------
__global__ __launch_bounds__(256) void conv_silu_k(
    const float* __restrict__ xz, const float* __restrict__ cw,
    const float* __restrict__ cb, float* __restrict__ xc)
{
    int idx = blockIdx.x * 256 + threadIdx.x;   // ROWS*D_INNER exact
    int d = idx & (D_INNER - 1);
    int row = idx >> 10;
    int t = row & (TT - 1);
    float4 w = *(const float4*)(cw + (size_t)d * 4);
    float acc = cb[d];
    if (t >= 3) {
        const float* base = xz + (size_t)(row - 3) * (2 * D_INNER) + d;
        acc = fmaf(base[0],    w.x, acc);
        acc = fmaf(base[2048], w.y, acc);
        acc = fmaf(base[4096], w.z, acc);
        acc = fmaf(base[6144], w.w, acc);
    } else {
        float wv[4] = {w.x, w.y, w.z, w.w};
        int bstart = row - t;
        #pragma unroll
        for (int j = 0; j < 4; ++j) {
            int ts = t + j - 3;
            if (ts >= 0) acc = fmaf(xz[(size_t)(bstart + ts) * (2 * D_INNER) + d], wv[j], acc);
        }
    }
    xc[idx] = silu_f(acc);
}

// ---------------- chunked selective scan (dt lives in XZ lower half, ld=2048) -------
__global__ __launch_bounds__(256) void scan_pass1_k(
    const float* __restrict__ dt, const float* __restrict__ xc,
    const float* __restrict__ xdbl, const float* __restrict__ A_log,
    float* __restrict__ hf, float* __restrict__ pf)
{
    int tid = threadIdx.x;
    int s = tid & 15, dl = tid >> 4;
    int d = blockIdx.x * 16 + dl;
    int c = blockIdx.y;
    int b = blockIdx.z;
    float Av = -__expf(A_log[d * 16 + s]);
    float h = 0.f, P = 1.f;
    int row0 = b * TT + c * CHL;
    for (int t = 0; t < CHL; ++t) {
        size_t row = (size_t)(row0 + t);
        float dtv = dt[row * (2 * D_INNER) + d];
        float xv  = xc[row * D_INNER + d];
        float Bv  = xdbl[row * 64 + DT_RANK + s];
        float dA  = __expf(dtv * Av);
        h = fmaf(dA, h, dtv * xv * Bv);
        P *= dA;
    }
    size_t o = ((((size_t)b * NCH + c) * D_INNER) + d) * 16 + s;
    hf[o] = h; pf[o] = P;
}

__global__ __launch_bounds__(256) void scan_combine_k(
    const float* __restrict__ hf, const float* __restrict__ pf,
    float* __restrict__ hin)
{
    int idx = blockIdx.x * 256 + threadIdx.x;   // BB*D_INNER*16 exact
    int b = idx >> 14;
    int rest = idx & 16383;
    float h = 0.f;
    for (int c = 0; c < NCH; ++c) {
        size_t o = (((size_t)b * NCH + c) * (D_INNER * 16)) + rest;
        hin[o] = h;
        h = fmaf(pf[o], h, hf[o]);
    }
}

__global__ __launch_bounds__(256) void scan_pass2_k(
    const float* __restrict__ dt, const float* __restrict__ xc,
    const float* __restrict__ xdbl, const float* __restrict__ A_log,
    const float* __restrict__ Dp, const float* __restrict__ hin,
    float* __restrict__ y)   // y written at row*2048+d (overwrites dt slot, safe in-wave)
{
    int tid = threadIdx.x;
    int s = tid & 15, dl = tid >> 4;
    int d = blockIdx.x * 16 + dl;
    int c = blockIdx.y;
    int b = blockIdx.z;
    float Av = -__expf(A_log[d * 16 + s]);
    float Dv = Dp[d];
    size_t ho = ((((size_t)b * NCH + c) * D_INNER) + d) * 16 + s;
    float h = hin[ho];
    int row0 = b * TT + c * CHL;
    for (int t = 0; t < CHL; ++t) {
        size_t row = (size_t)(row0 + t);
        float dtv = dt[row * (2 * D_INNER) + d];
        float xv  = xc[row * D_INNER + d];
        float Bv  = xdbl[row * 64 + DT_RANK + s];
        float Cv  = xdbl[row * 64 + DT_RANK + D_STATE + s];
        float dA  = __expf(dtv * Av);
        h = fmaf(dA, h, dtv * xv * Bv);
        float p = h * Cv;
        p += __shfl_xor(p, 1);
        p += __shfl_xor(p, 2);
        p += __shfl_xor(p, 4);
        p += __shfl_xor(p, 8);
        if (s == 0) y[row * (2 * D_INNER) + d] = fmaf(xv, Dv, p);
    }
}

// ---------------- u = y * silu(z) -> bf16 ----------------
__global__ __launch_bounds__(256) void ymulz_k(
    const float* __restrict__ xz, __hip_bfloat16* __restrict__ u)
{
    int idx = blockIdx.x * 256 + threadIdx.x;   // ROWS*D_INNER exact
    int d = idx & (D_INNER - 1);
    size_t row = (size_t)(idx >> 10);
    float yv = xz[row * (2 * D_INNER) + d];
    float zv = xz[row * (2 * D_INNER) + D_INNER + d];
    u[idx] = __float2bfloat16(yv * silu_f(zv));
}

__global__ __launch_bounds__(256) void copy_k(const float* __restrict__ src, float* __restrict__ dst, int n)
{
    int idx = blockIdx.x * 256 + threadIdx.x;
    if (idx < n) dst[idx] = src[idx];
}

extern "C" void kernel_launch(void* const* d_in, const int* in_sizes, int n_in,
                              void* d_out, int out_size, void* d_ws, size_t ws_size,
                              hipStream_t stream)
{
    const float* state   = (const float*)d_in[0];
    const float* pact    = (const float*)d_in[1];
    const float* W_state = (const float*)d_in[2];
    const float* b_state = (const float*)d_in[3];
    const float* W_act   = (const float*)d_in[4];
    const float* b_act   = (const float*)d_in[5];
    const float* W_fuse  = (const float*)d_in[6];
    const float* b_fuse  = (const float*)d_in[7];
    const float* g_fuse  = (const float*)d_in[8];
    const float* norm_w  = (const float*)d_in[9];
    const float* W_in    = (const float*)d_in[10];
    const float* conv_w  = (const float*)d_in[11];
    const float* conv_b  = (const float*)d_in[12];
    const float* W_x     = (const float*)d_in[13];
    const float* W_dt    = (const float*)d_in[14];
    const float* b_dt    = (const float*)d_in[15];
    const float* A_log   = (const float*)d_in[16];
    const float* Dp      = (const float*)d_in[17];
    const float* W_out   = (const float*)d_in[18];
    const float* W_head  = (const float*)d_in[19];
    const float* b_head  = (const float*)d_in[20];

    float* ws = (float*)d_ws;
    float* X    = ws;                     // 8192*512 fp32
    float* R1   = ws + 4194304;           // EMB_BF (bf16 8192*640) / XNORM_BF (bf16 8192*512) / HIN
    float* XZ   = ws + 6815744;           // 8192*2048 fp32 (dt aliased in lower half)
    float* XC   = ws + 23592960;          // 8192*1024 fp32
    float* R2   = ws + 31981568;          // HF+PF (2*2097152 fp32) / U_BF (bf16 8192*1024)
    float* XDBL = ws + 36175872;          // 8192*64 fp32
    float* WT_f = ws + 36700160;          // transposed bf16 weights (3,309,568 floats)
    // end: 40,009,728 floats = 160 MB

    __hip_bfloat16* EMB_BF   = (__hip_bfloat16*)R1;
    __hip_bfloat16* XNORM_BF = (__hip_bfloat16*)R1;
    float*          HIN      = R1;
    float*          HF       = R2;
    float*          PF       = R2 + 2097152;
    __hip_bfloat16* U_BF     = (__hip_bfloat16*)R2;
    __hip_bfloat16* WT       = (__hip_bfloat16*)WT_f;
    __hip_bfloat16* WfuseT   = WT;                          // 640*512
    __hip_bfloat16* WinT     = WT + 327680;                 // 4 * 2048*512
    __hip_bfloat16* WoutT    = WT + 4521984;                // 4 * 512*1024

    dim3 b256(256);

    // weight transpose+cast (fp32 (K,N) -> bf16 (N,K))
    transcast_k<<<dim3(8, 10, 1),  b256, 0, stream>>>(W_fuse, WfuseT, FUSE_IN, D_MODEL);
    transcast_k<<<dim3(32, 8, 4),  b256, 0, stream>>>(W_in,   WinT,   D_MODEL, 2 * D_INNER);
    transcast_k<<<dim3(8, 16, 4),  b256, 0, stream>>>(W_out,  WoutT,  D_INNER, D_MODEL);

    embed_k<<<ROWS * FUSE_IN / 256, b256, 0, stream>>>(state, pact, W_state, b_state, W_act, b_act, EMB_BF);
    gemm_bf16<<<dim3(64, 4), b256, 0, stream>>>(EMB_BF, WfuseT, b_fuse, X,
        ROWS, D_MODEL, FUSE_IN, FUSE_IN, FUSE_IN, D_MODEL, 1);
    rmsnorm_k<<<ROWS, b256, 0, stream>>>(X, g_fuse, X, 1);

    for (int L = 0; L < N_LAYERS; ++L) {
        const float* cw  = conv_w + (size_t)L * D_INNER * 4;
        const float* cb  = conv_b + (size_t)L * D_INNER;
        const float* Wx  = W_x   + (size_t)L * D_INNER * 64;
        const float* Wd  = W_dt  + (size_t)L * DT_RANK * D_INNER;
        const float* bd  = b_dt  + (size_t)L * D_INNER;
        const float* Al  = A_log + (size_t)L * D_INNER * D_STATE;
        const float* Dpl = Dp    + (size_t)L * D_INNER;
        __hip_bfloat16* WiT = WinT  + (size_t)L * 2 * D_INNER * D_MODEL;
        __hip_bfloat16* WoT = WoutT + (size_t)L * D_MODEL * D_INNER;

        rmsnorm_k<<<ROWS, b256, 0, stream>>>(X, norm_w + L * D_MODEL, XNORM_BF, 2);
        gemm_bf16<<<dim3(64, 16), b256, 0, stream>>>(XNORM_BF, WiT, nullptr, XZ,
            ROWS, 2 * D_INNER, D_MODEL, D_MODEL, D_MODEL, 2 * D_INNER, 0);
        conv_silu_k<<<ROWS * D_INNER / 256, b256, 0, stream>>>(XZ, cw, cb, XC);
        gemm_f32<<<dim3(128, 1), b256, 0, stream>>>(XC, Wx, nullptr, XDBL,
            ROWS, 64, D_INNER, D_INNER, 64, 64, 0);
        gemm_f32<<<dim3(128, 16), b256, 0, stream>>>(XDBL, Wd, bd, XZ,
            ROWS, D_INNER, DT_RANK, 64, D_INNER, 2 * D_INNER, 3);   // dt -> XZ lower half
        scan_pass1_k<<<dim3(64, NCH, BB), b256, 0, stream>>>(XZ, XC, XDBL, Al, HF, PF);
        scan_combine_k<<<BB * D_INNER * 16 / 256, b256, 0, stream>>>(HF, PF, HIN);
        scan_pass2_k<<<dim3(64, NCH, BB), b256, 0, stream>>>(XZ, XC, XDBL, Al, Dpl, HIN, XZ);
        ymulz_k<<<ROWS * D_INNER / 256, b256, 0, stream>>>(XZ, U_BF);
        gemm_bf16<<<dim3(64, 4), b256, 0, stream>>>(U_BF, WoT, nullptr, X,
            ROWS, D_MODEL, D_INNER, D_INNER, D_INNER, D_MODEL, 4);
    }

    gemm_f32<<<dim3(128, 1), b256, 0, stream>>>(X, W_head, b_head, (float*)d_out,
        ROWS, TGT_DIM, D_MODEL, D_MODEL, TGT_DIM, TGT_DIM, 1);
    copy_k<<<ROWS * D_MODEL / 256, b256, 0, stream>>>(X, (float*)d_out + ROWS * TGT_DIM, ROWS * D_MODEL);
}

// Round 3
// 1855.987 us; speedup vs baseline: 2.1380x; 1.2072x over previous
//
#include <hip/hip_runtime.h>
#include <hip/hip_bf16.h>
#include <math.h>

#define D_MODEL 512
#define D_INNER 1024
#define D_STATE 16
#define DT_RANK 32
#define N_LAYERS 4
#define BB 8
#define TT 1024
#define ROWS (BB * TT)      // 8192
#define IN_DIM 32
#define ACT_DIM 4
#define TGT_DIM 32
#define ACT_EMB 128
#define FUSE_IN (D_MODEL + ACT_EMB)  // 640
#define NCH 16
#define CHL (TT / NCH)      // 64

typedef __attribute__((ext_vector_type(8))) short short8;   // 8 bf16 (4 VGPRs)
typedef __attribute__((ext_vector_type(4))) float f32x4;

__device__ __forceinline__ float silu_f(float x) { return x / (1.f + __expf(-x)); }

#define GL2LDS(g, l) __builtin_amdgcn_global_load_lds( \
    (const __attribute__((address_space(1))) void*)(g), \
    (__attribute__((address_space(3))) void*)(l), 16, 0, 0)

// ---------------- transpose+cast weights: in (K,N) fp32 -> out (N,K) bf16 ---------
__global__ __launch_bounds__(256) void transcast_k(
    const float* __restrict__ in, __hip_bfloat16* __restrict__ out, int K, int N)
{
    __shared__ float t[64][65];
    size_t zoff = (size_t)blockIdx.z * K * N;
    in += zoff; out += zoff;
    int k0 = blockIdx.y * 64, n0 = blockIdx.x * 64;
    int ln = threadIdx.x & 63, gr = threadIdx.x >> 6;
    #pragma unroll
    for (int i = 0; i < 16; ++i) {
        int kr = gr + i * 4;
        t[kr][ln] = in[(size_t)(k0 + kr) * N + n0 + ln];
    }
    __syncthreads();
    #pragma unroll
    for (int i = 0; i < 16; ++i) {
        int nr = gr + i * 4;
        out[(size_t)(n0 + nr) * K + k0 + ln] = __float2bfloat16(t[ln][nr]);
    }
}

// ---------------- embed: s_emb | silu(a_emb) -> emb bf16 (ROWS x 640) ----------------
__global__ __launch_bounds__(256) void embed_k(
    const float* __restrict__ state, const float* __restrict__ act,
    const float* __restrict__ W_state, const float* __restrict__ b_state,
    const float* __restrict__ W_act, const float* __restrict__ b_act,
    __hip_bfloat16* __restrict__ emb)
{
    int idx = blockIdx.x * 256 + threadIdx.x;   // ROWS*FUSE_IN exact
    int r = idx / FUSE_IN;
    int c = idx - r * FUSE_IN;
    float acc;
    if (c < D_MODEL) {
        acc = b_state[c];
        const float* sp = state + (size_t)r * IN_DIM;
        #pragma unroll
        for (int k = 0; k < IN_DIM; ++k) acc = fmaf(sp[k], W_state[k * D_MODEL + c], acc);
    } else {
        int cc = c - D_MODEL;
        acc = b_act[cc];
        const float* ap = act + (size_t)r * ACT_DIM;
        #pragma unroll
        for (int k = 0; k < ACT_DIM; ++k) acc = fmaf(ap[k], W_act[k * ACT_EMB + cc], acc);
        acc = silu_f(acc);
    }
    emb[idx] = __float2bfloat16(acc);
}

// ---------------- MFMA bf16 GEMM: C(M,N) fp32 = A(M,K)bf16 @ B^T(N,K)bf16 ----------
// BM=128, BN=128, BK=64; 256 threads = 4 waves, each wave 64x64.
// flags: 1 = add bias, 4 = residual add into existing C.
__global__ __launch_bounds__(256) void gemm_bf16(
    const __hip_bfloat16* __restrict__ A, const __hip_bfloat16* __restrict__ B,
    const float* __restrict__ bias, float* __restrict__ C,
    int M, int N, int K, int lda, int ldb, int ldc, int flags)
{
    __shared__ __hip_bfloat16 As[128 * 64];
    __shared__ __hip_bfloat16 Bs[128 * 64];
    const int tid  = threadIdx.x;
    const int wave = tid >> 6;
    const int lane = tid & 63;
    const size_t bm = (size_t)blockIdx.x * 128;
    const size_t bn = (size_t)blockIdx.y * 128;

    const int srow  = (lane >> 3);          // 0..7 within chunk
    const int gkblk = (lane & 7) ^ (lane >> 3);   // XOR swizzle
    const int wr = wave >> 1, wc = wave & 1;
    const int mbase = wr * 64 + (lane & 15);
    const int nbase = wc * 64 + (lane & 15);
    const int quad  = lane >> 4;            // 0..3
    const int swz   = lane & 7;

    f32x4 acc[4][4] = {};

    for (int k0 = 0; k0 < K; k0 += 64) {
        #pragma unroll
        for (int r = 0; r < 4; ++r) {
            int c2 = r * 4 + wave;
            int row = c2 * 8 + srow;
            const __hip_bfloat16* ga = A + (bm + row) * lda + k0 + gkblk * 8;
            GL2LDS(ga, As + (size_t)c2 * 512);
            const __hip_bfloat16* gb = B + (bn + row) * ldb + k0 + gkblk * 8;
            GL2LDS(gb, Bs + (size_t)c2 * 512);
        }
        __syncthreads();
        #pragma unroll
        for (int kk = 0; kk < 2; ++kk) {
            int kblk = kk * 4 + quad;
            int p = (kblk ^ swz) * 8;
            short8 af[4], bf[4];
            #pragma unroll
            for (int mi = 0; mi < 4; ++mi)
                af[mi] = *reinterpret_cast<const short8*>(&As[(mbase + mi * 16) * 64 + p]);
            #pragma unroll
            for (int ni = 0; ni < 4; ++ni)
                bf[ni] = *reinterpret_cast<const short8*>(&Bs[(nbase + ni * 16) * 64 + p]);
            #pragma unroll
            for (int mi = 0; mi < 4; ++mi)
                #pragma unroll
                for (int ni = 0; ni < 4; ++ni)
                    acc[mi][ni] = __builtin_amdgcn_mfma_f32_16x16x32_bf16(
                        af[mi], bf[ni], acc[mi][ni], 0, 0, 0);
        }
        __syncthreads();
    }

    #pragma unroll
    for (int ni = 0; ni < 4; ++ni) {
        int gn = (int)bn + wc * 64 + ni * 16 + (lane & 15);
        float bv = (flags & 1) ? bias[gn] : 0.f;
        #pragma unroll
        for (int mi = 0; mi < 4; ++mi) {
            #pragma unroll
            for (int r = 0; r < 4; ++r) {
                size_t gm = bm + wr * 64 + mi * 16 + quad * 4 + r;
                float v = acc[mi][ni][r] + bv;
                size_t o = gm * ldc + gn;
                if (flags & 4) v += C[o];
                C[o] = v;
            }
        }
    }
}

// ---------------- generic fp32 GEMM (small shapes): flags 1=bias,2=softplus,4=residual
#define BM 64
#define BN 64
#define BK 16
__global__ __launch_bounds__(256) void gemm_f32(
    const float* __restrict__ A, const float* __restrict__ B,
    const float* __restrict__ bias, float* __restrict__ C,
    int M, int N, int K, int lda, int ldb, int ldc, int flags)
{
    __shared__ __align__(16) float As[BK][BM + 4];
    __shared__ __align__(16) float Bs[BK][BN];
    const int tid = threadIdx.x;
    const int bm = blockIdx.x * BM;
    const int bn = blockIdx.y * BN;
    const int tx = tid & 15;
    const int ty = tid >> 4;
    float acc[4][4] = {};
    for (int k0 = 0; k0 < K; k0 += BK) {
        #pragma unroll
        for (int i = 0; i < 4; ++i) {
            int l = tid + 256 * i;
            int m = l >> 4, kk = l & 15;
            int gm = bm + m, gk = k0 + kk;
            As[kk][m] = (gm < M && gk < K) ? A[(size_t)gm * lda + gk] : 0.f;
        }
        #pragma unroll
        for (int i = 0; i < 4; ++i) {
            int l = tid + 256 * i;
            int kk = l >> 6, n = l & 63;
            int gk = k0 + kk, gn = bn + n;
            Bs[kk][n] = (gk < K && gn < N) ? B[(size_t)gk * ldb + gn] : 0.f;
        }
        __syncthreads();
        #pragma unroll
        for (int kk = 0; kk < BK; ++kk) {
            float4 av = *(const float4*)&As[kk][ty * 4];
            float4 bv = *(const float4*)&Bs[kk][tx * 4];
            float a[4] = {av.x, av.y, av.z, av.w};
            float b[4] = {bv.x, bv.y, bv.z, bv.w};
            #pragma unroll
            for (int i = 0; i < 4; ++i)
                #pragma unroll
                for (int j = 0; j < 4; ++j)
                    acc[i][j] = fmaf(a[i], b[j], acc[i][j]);
        }
        __syncthreads();
    }
    #pragma unroll
    for (int i = 0; i < 4; ++i) {
        int gm = bm + ty * 4 + i;
        if (gm >= M) continue;
        #pragma unroll
        for (int j = 0; j < 4; ++j) {
            int gn = bn + tx * 4 + j;
            if (gn >= N) continue;
            float v = acc[i][j];
            if (flags & 1) v += bias[gn];
            if (flags & 2) v = (v > 20.f) ? v : log1pf(__expf(v));
            size_t o = (size_t)gm * ldc + gn;
            if (flags & 4) v += C[o];
            C[o] = v;
        }
    }
}

// ---------------- split-K fp32 GEMM: C += partials via atomicAdd -------------------
// grid.z = K-slices of length klen. C must be zeroed first. flags: 1 = bias (slice 0).
__global__ __launch_bounds__(256) void gemm_f32_splitk(
    const float* __restrict__ A, const float* __restrict__ B,
    const float* __restrict__ bias, float* __restrict__ C,
    int M, int N, int K, int lda, int ldb, int ldc, int flags, int klen)
{
    __shared__ __align__(16) float As[BK][BM + 4];
    __shared__ __align__(16) float Bs[BK][BN];
    const int tid = threadIdx.x;
    const int bm = blockIdx.x * BM;
    const int bn = blockIdx.y * BN;
    const int kbeg = blockIdx.z * klen;
    const int kend = min(K, kbeg + klen);
    const int tx = tid & 15;
    const int ty = tid >> 4;
    float acc[4][4] = {};
    for (int k0 = kbeg; k0 < kend; k0 += BK) {
        #pragma unroll
        for (int i = 0; i < 4; ++i) {
            int l = tid + 256 * i;
            int m = l >> 4, kk = l & 15;
            int gm = bm + m, gk = k0 + kk;
            As[kk][m] = (gm < M && gk < K) ? A[(size_t)gm * lda + gk] : 0.f;
        }
        #pragma unroll
        for (int i = 0; i < 4; ++i) {
            int l = tid + 256 * i;
            int kk = l >> 6, n = l & 63;
            int gk = k0 + kk, gn = bn + n;
            Bs[kk][n] = (gk < K && gn < N) ? B[(size_t)gk * ldb + gn] : 0.f;
        }
        __syncthreads();
        #pragma unroll
        for (int kk = 0; kk < BK; ++kk) {
            float4 av = *(const float4*)&As[kk][ty * 4];
            float4 bv = *(const float4*)&Bs[kk][tx * 4];
            float a[4] = {av.x, av.y, av.z, av.w};
            float b[4] = {bv.x, bv.y, bv.z, bv.w};
            #pragma unroll
            for (int i = 0; i < 4; ++i)
                #pragma unroll
                for (int j = 0; j < 4; ++j)
                    acc[i][j] = fmaf(a[i], b[j], acc[i][j]);
        }
        __syncthreads();
    }
    #pragma unroll
    for (int i = 0; i < 4; ++i) {
        int gm = bm + ty * 4 + i;
        if (gm >= M) continue;
        #pragma unroll
        for (int j = 0; j < 4; ++j) {
            int gn = bn + tx * 4 + j;
            if (gn >= N) continue;
            float v = acc[i][j];
            if ((flags & 1) && blockIdx.z == 0) v += bias[gn];
            atomicAdd(&C[(size_t)gm * ldc + gn], v);
        }
    }
}

__global__ __launch_bounds__(256) void zero_k(float* __restrict__ p, int n)
{
    int idx = blockIdx.x * 256 + threadIdx.x;
    if (idx < n) p[idx] = 0.f;
}

// ---------------- rmsnorm over 512; flags: 1 = silu, 2 = bf16 output ----------------
__global__ __launch_bounds__(256) void rmsnorm_k(
    const float* __restrict__ in, const float* __restrict__ w,
    void* __restrict__ outp, int flags)
{
    int row = blockIdx.x;
    int tid = threadIdx.x;
    const float* ip = in + (size_t)row * D_MODEL;
    float v0 = ip[tid], v1 = ip[tid + 256];
    float ss = v0 * v0 + v1 * v1;
    #pragma unroll
    for (int off = 32; off >= 1; off >>= 1) ss += __shfl_xor(ss, off, 64);
    __shared__ float red[4];
    if ((tid & 63) == 0) red[tid >> 6] = ss;
    __syncthreads();
    float tot = red[0] + red[1] + red[2] + red[3];
    float sc = rsqrtf(tot * (1.f / D_MODEL) + 1e-6f);
    float o0 = v0 * sc * w[tid];
    float o1 = v1 * sc * w[tid + 256];
    if (flags & 1) { o0 = silu_f(o0); o1 = silu_f(o1); }
    if (flags & 2) {
        __hip_bfloat16* op = (__hip_bfloat16*)outp + (size_t)row * D_MODEL;
        op[tid] = __float2bfloat16(o0); op[tid + 256] = __float2bfloat16(o1);
    } else {
        float* op = (float*)outp + (size_t)row * D_MODEL;
        op[tid] = o0; op[tid + 256] = o1;
    }
}

// ---------------- causal depthwise conv (k=4) + bias + silu ----------------
__global__ __launch_bounds__(256) void conv_silu_k(
    const float* __restrict__ xz, const float* __restrict__ cw,
    const float* __restrict__ cb, float* __restrict__ xc)
{
    int idx = blockIdx.x * 256 + threadIdx.x;   // ROWS*D_INNER exact
    int d = idx & (D_INNER - 1);
    int row = idx >> 10;
    int t = row & (TT - 1);
    float4 w = *(const float4*)(cw + (size_t)d * 4);
    float acc = cb[d];
    if (t >= 3) {
        const float* base = xz + (size_t)(row - 3) * (2 * D_INNER) + d;
        acc = fmaf(base[0],    w.x, acc);
        acc = fmaf(base[2048], w.y, acc);
        acc = fmaf(base[4096], w.z, acc);
        acc = fmaf(base[6144], w.w, acc);
    } else {
        float wv[4] = {w.x, w.y, w.z, w.w};
        int bstart = row - t;
        #pragma unroll
        for (int j = 0; j < 4; ++j) {
            int ts = t + j - 3;
            if (ts >= 0) acc = fmaf(xz[(size_t)(bstart + ts) * (2 * D_INNER) + d], wv[j], acc);
        }
    }
    xc[idx] = silu_f(acc);
}

// ---------------- chunked selective scan (dt lives in XZ lower half, ld=2048) -------
__global__ __launch_bounds__(256) void scan_pass1_k(
    const float* __restrict__ dt, const float* __restrict__ xc,
    const float* __restrict__ xdbl, const float* __restrict__ A_log,
    float* __restrict__ hf, float* __restrict__ pf)
{
    int tid = threadIdx.x;
    int s = tid & 15, dl = tid >> 4;
    int d = blockIdx.x * 16 + dl;
    int c = blockIdx.y;
    int b = blockIdx.z;
    float Av = -__expf(A_log[d * 16 + s]);
    float h = 0.f, P = 1.f;
    int row0 = b * TT + c * CHL;
    for (int t = 0; t < CHL; ++t) {
        size_t row = (size_t)(row0 + t);
        float dtv = dt[row * (2 * D_INNER) + d];
        float xv  = xc[row * D_INNER + d];
        float Bv  = xdbl[row * 64 + DT_RANK + s];
        float dA  = __expf(dtv * Av);
        h = fmaf(dA, h, dtv * xv * Bv);
        P *= dA;
    }
    size_t o = ((((size_t)b * NCH + c) * D_INNER) + d) * 16 + s;
    hf[o] = h; pf[o] = P;
}

__global__ __launch_bounds__(256) void scan_combine_k(
    const float* __restrict__ hf, const float* __restrict__ pf,
    float* __restrict__ hin)
{
    int idx = blockIdx.x * 256 + threadIdx.x;   // BB*D_INNER*16 exact
    int b = idx >> 14;
    int rest = idx & 16383;
    float h = 0.f;
    for (int c = 0; c < NCH; ++c) {
        size_t o = (((size_t)b * NCH + c) * (D_INNER * 16)) + rest;
        hin[o] = h;
        h = fmaf(pf[o], h, hf[o]);
    }
}

__global__ __launch_bounds__(256) void scan_pass2_k(
    const float* __restrict__ dt, const float* __restrict__ xc,
    const float* __restrict__ xdbl, const float* __restrict__ A_log,
    const float* __restrict__ Dp, const float* __restrict__ hin,
    float* __restrict__ y)   // y written at row*2048+d (overwrites dt slot, safe in-wave)
{
    int tid = threadIdx.x;
    int s = tid & 15, dl = tid >> 4;
    int d = blockIdx.x * 16 + dl;
    int c = blockIdx.y;
    int b = blockIdx.z;
    float Av = -__expf(A_log[d * 16 + s]);
    float Dv = Dp[d];
    size_t ho = ((((size_t)b * NCH + c) * D_INNER) + d) * 16 + s;
    float h = hin[ho];
    int row0 = b * TT + c * CHL;
    for (int t = 0; t < CHL; ++t) {
        size_t row = (size_t)(row0 + t);
        float dtv = dt[row * (2 * D_INNER) + d];
        float xv  = xc[row * D_INNER + d];
        float Bv  = xdbl[row * 64 + DT_RANK + s];
        float Cv  = xdbl[row * 64 + DT_RANK + D_STATE + s];
        float dA  = __expf(dtv * Av);
        h = fmaf(dA, h, dtv * xv * Bv);
        float p = h * Cv;
        p += __shfl_xor(p, 1);
        p += __shfl_xor(p, 2);
        p += __shfl_xor(p, 4);
        p += __shfl_xor(p, 8);
        if (s == 0) y[row * (2 * D_INNER) + d] = fmaf(xv, Dv, p);
    }
}

// ---------------- u = y * silu(z) -> bf16 ----------------
__global__ __launch_bounds__(256) void ymulz_k(
    const float* __restrict__ xz, __hip_bfloat16* __restrict__ u)
{
    int idx = blockIdx.x * 256 + threadIdx.x;   // ROWS*D_INNER exact
    int d = idx & (D_INNER - 1);
    size_t row = (size_t)(idx >> 10);
    float yv = xz[row * (2 * D_INNER) + d];
    float zv = xz[row * (2 * D_INNER) + D_INNER + d];
    u[idx] = __float2bfloat16(yv * silu_f(zv));
}

__global__ __launch_bounds__(256) void copy_k(const float* __restrict__ src, float* __restrict__ dst, int n)
{
    int idx = blockIdx.x * 256 + threadIdx.x;
    if (idx < n) dst[idx] = src[idx];
}

extern "C" void kernel_launch(void* const* d_in, const int* in_sizes, int n_in,
                              void* d_out, int out_size, void* d_ws, size_t ws_size,
                              hipStream_t stream)
{
    const float* state   = (const float*)d_in[0];
    const float* pact    = (const float*)d_in[1];
    const float* W_state = (const float*)d_in[2];
    const float* b_state = (const float*)d_in[3];
    const float* W_act   = (const float*)d_in[4];
    const float* b_act   = (const float*)d_in[5];
    const float* W_fuse  = (const float*)d_in[6];
    const float* b_fuse  = (const float*)d_in[7];
    const float* g_fuse  = (const float*)d_in[8];
    const float* norm_w  = (const float*)d_in[9];
    const float* W_in    = (const float*)d_in[10];
    const float* conv_w  = (const float*)d_in[11];
    const float* conv_b  = (const float*)d_in[12];
    const float* W_x     = (const float*)d_in[13];
    const float* W_dt    = (const float*)d_in[14];
    const float* b_dt    = (const float*)d_in[15];
    const float* A_log   = (const float*)d_in[16];
    const float* Dp      = (const float*)d_in[17];
    const float* W_out   = (const float*)d_in[18];
    const float* W_head  = (const float*)d_in[19];
    const float* b_head  = (const float*)d_in[20];

    float* ws = (float*)d_ws;
    float* X    = ws;                     // 8192*512 fp32
    float* R1   = ws + 4194304;           // EMB_BF / XNORM_BF / HIN
    float* XZ   = ws + 6815744;           // 8192*2048 fp32 (dt aliased in lower half)
    float* XC   = ws + 23592960;          // 8192*1024 fp32
    float* R2   = ws + 31981568;          // HF+PF / U_BF
    float* XDBL = ws + 36175872;          // 8192*64 fp32
    float* WT_f = ws + 36700160;          // transposed bf16 weights
    // end: 40,009,728 floats = 160 MB

    __hip_bfloat16* EMB_BF   = (__hip_bfloat16*)R1;
    __hip_bfloat16* XNORM_BF = (__hip_bfloat16*)R1;
    float*          HIN      = R1;
    float*          HF       = R2;
    float*          PF       = R2 + 2097152;
    __hip_bfloat16* U_BF     = (__hip_bfloat16*)R2;
    __hip_bfloat16* WT       = (__hip_bfloat16*)WT_f;
    __hip_bfloat16* WfuseT   = WT;                          // 640*512
    __hip_bfloat16* WinT     = WT + 327680;                 // 4 * 2048*512
    __hip_bfloat16* WoutT    = WT + 4521984;                // 4 * 512*1024

    dim3 b256(256);

    transcast_k<<<dim3(8, 10, 1),  b256, 0, stream>>>(W_fuse, WfuseT, FUSE_IN, D_MODEL);
    transcast_k<<<dim3(32, 8, 4),  b256, 0, stream>>>(W_in,   WinT,   D_MODEL, 2 * D_INNER);
    transcast_k<<<dim3(8, 16, 4),  b256, 0, stream>>>(W_out,  WoutT,  D_INNER, D_MODEL);

    embed_k<<<ROWS * FUSE_IN / 256, b256, 0, stream>>>(state, pact, W_state, b_state, W_act, b_act, EMB_BF);
    gemm_bf16<<<dim3(64, 4), b256, 0, stream>>>(EMB_BF, WfuseT, b_fuse, X,
        ROWS, D_MODEL, FUSE_IN, FUSE_IN, FUSE_IN, D_MODEL, 1);
    rmsnorm_k<<<ROWS, b256, 0, stream>>>(X, g_fuse, X, 1);

    for (int L = 0; L < N_LAYERS; ++L) {
        const float* cw  = conv_w + (size_t)L * D_INNER * 4;
        const float* cb  = conv_b + (size_t)L * D_INNER;
        const float* Wx  = W_x   + (size_t)L * D_INNER * 64;
        const float* Wd  = W_dt  + (size_t)L * DT_RANK * D_INNER;
        const float* bd  = b_dt  + (size_t)L * D_INNER;
        const float* Al  = A_log + (size_t)L * D_INNER * D_STATE;
        const float* Dpl = Dp    + (size_t)L * D_INNER;
        __hip_bfloat16* WiT = WinT  + (size_t)L * 2 * D_INNER * D_MODEL;
        __hip_bfloat16* WoT = WoutT + (size_t)L * D_MODEL * D_INNER;

        rmsnorm_k<<<ROWS, b256, 0, stream>>>(X, norm_w + L * D_MODEL, XNORM_BF, 2);
        gemm_bf16<<<dim3(64, 16), b256, 0, stream>>>(XNORM_BF, WiT, nullptr, XZ,
            ROWS, 2 * D_INNER, D_MODEL, D_MODEL, D_MODEL, 2 * D_INNER, 0);
        conv_silu_k<<<ROWS * D_INNER / 256, b256, 0, stream>>>(XZ, cw, cb, XC);
        // W_x GEMM: split-K (K=1024 -> 8 slices of 128), atomic accumulate
        zero_k<<<ROWS * 64 / 256, b256, 0, stream>>>(XDBL, ROWS * 64);
        gemm_f32_splitk<<<dim3(128, 1, 8), b256, 0, stream>>>(XC, Wx, nullptr, XDBL,
            ROWS, 64, D_INNER, D_INNER, 64, 64, 0, 128);
        gemm_f32<<<dim3(128, 16), b256, 0, stream>>>(XDBL, Wd, bd, XZ,
            ROWS, D_INNER, DT_RANK, 64, D_INNER, 2 * D_INNER, 3);   // dt -> XZ lower half
        scan_pass1_k<<<dim3(64, NCH, BB), b256, 0, stream>>>(XZ, XC, XDBL, Al, HF, PF);
        scan_combine_k<<<BB * D_INNER * 16 / 256, b256, 0, stream>>>(HF, PF, HIN);
        scan_pass2_k<<<dim3(64, NCH, BB), b256, 0, stream>>>(XZ, XC, XDBL, Al, Dpl, HIN, XZ);
        ymulz_k<<<ROWS * D_INNER / 256, b256, 0, stream>>>(XZ, U_BF);
        gemm_bf16<<<dim3(64, 4), b256, 0, stream>>>(U_BF, WoT, nullptr, X,
            ROWS, D_MODEL, D_INNER, D_INNER, D_INNER, D_MODEL, 4);
    }

    // head: split-K (K=512 -> 8 slices of 64), atomic accumulate, bias from slice 0
    zero_k<<<ROWS * TGT_DIM / 256, b256, 0, stream>>>((float*)d_out, ROWS * TGT_DIM);
    gemm_f32_splitk<<<dim3(128, 1, 8), b256, 0, stream>>>(X, W_head, b_head, (float*)d_out,
        ROWS, TGT_DIM, D_MODEL, D_MODEL, TGT_DIM, TGT_DIM, 1, 64);
    copy_k<<<ROWS * D_MODEL / 256, b256, 0, stream>>>(X, (float*)d_out + ROWS * TGT_DIM, ROWS * D_MODEL);
}

// Round 4
// 1483.445 us; speedup vs baseline: 2.6749x; 1.2511x over previous
//
#include <hip/hip_runtime.h>
#include <hip/hip_bf16.h>
#include <math.h>

#define D_MODEL 512
#define D_INNER 1024
#define D_STATE 16
#define DT_RANK 32
#define N_LAYERS 4
#define BB 8
#define TT 1024
#define ROWS (BB * TT)      // 8192
#define IN_DIM 32
#define ACT_DIM 4
#define TGT_DIM 32
#define ACT_EMB 128
#define FUSE_IN (D_MODEL + ACT_EMB)  // 640
#define NCH 16
#define CHL (TT / NCH)      // 64

typedef __attribute__((ext_vector_type(8))) short short8;   // 8 bf16 (4 VGPRs)
typedef __attribute__((ext_vector_type(4))) float f32x4;

__device__ __forceinline__ float silu_f(float x) { return x / (1.f + __expf(-x)); }

#define GL2LDS(g, l) __builtin_amdgcn_global_load_lds( \
    (const __attribute__((address_space(1))) void*)(g), \
    (__attribute__((address_space(3))) void*)(l), 16, 0, 0)

// ---------------- transpose+cast weights: in (K,N) fp32 -> out (N,K) bf16 ---------
__global__ __launch_bounds__(256) void transcast_k(
    const float* __restrict__ in, __hip_bfloat16* __restrict__ out, int K, int N)
{
    __shared__ float t[64][65];
    size_t zoff = (size_t)blockIdx.z * K * N;
    in += zoff; out += zoff;
    int k0 = blockIdx.y * 64, n0 = blockIdx.x * 64;
    int ln = threadIdx.x & 63, gr = threadIdx.x >> 6;
    #pragma unroll
    for (int i = 0; i < 16; ++i) {
        int kr = gr + i * 4;
        t[kr][ln] = in[(size_t)(k0 + kr) * N + n0 + ln];
    }
    __syncthreads();
    #pragma unroll
    for (int i = 0; i < 16; ++i) {
        int nr = gr + i * 4;
        out[(size_t)(n0 + nr) * K + k0 + ln] = __float2bfloat16(t[ln][nr]);
    }
}

// ---------------- embed: s_emb | silu(a_emb) -> emb bf16 (ROWS x 640) ----------------
__global__ __launch_bounds__(256) void embed_k(
    const float* __restrict__ state, const float* __restrict__ act,
    const float* __restrict__ W_state, const float* __restrict__ b_state,
    const float* __restrict__ W_act, const float* __restrict__ b_act,
    __hip_bfloat16* __restrict__ emb)
{
    int idx = blockIdx.x * 256 + threadIdx.x;   // ROWS*FUSE_IN exact
    int r = idx / FUSE_IN;
    int c = idx - r * FUSE_IN;
    float acc;
    if (c < D_MODEL) {
        acc = b_state[c];
        const float* sp = state + (size_t)r * IN_DIM;
        #pragma unroll
        for (int k = 0; k < IN_DIM; ++k) acc = fmaf(sp[k], W_state[k * D_MODEL + c], acc);
    } else {
        int cc = c - D_MODEL;
        acc = b_act[cc];
        const float* ap = act + (size_t)r * ACT_DIM;
        #pragma unroll
        for (int k = 0; k < ACT_DIM; ++k) acc = fmaf(ap[k], W_act[k * ACT_EMB + cc], acc);
        acc = silu_f(acc);
    }
    emb[idx] = __float2bfloat16(acc);
}

// ---------------- MFMA bf16 GEMM: C(M,N) fp32 = A(M,K)bf16 @ B^T(N,K)bf16 ----------
__global__ __launch_bounds__(256) void gemm_bf16(
    const __hip_bfloat16* __restrict__ A, const __hip_bfloat16* __restrict__ B,
    const float* __restrict__ bias, float* __restrict__ C,
    int M, int N, int K, int lda, int ldb, int ldc, int flags)
{
    __shared__ __hip_bfloat16 As[128 * 64];
    __shared__ __hip_bfloat16 Bs[128 * 64];
    const int tid  = threadIdx.x;
    const int wave = tid >> 6;
    const int lane = tid & 63;
    const size_t bm = (size_t)blockIdx.x * 128;
    const size_t bn = (size_t)blockIdx.y * 128;

    const int srow  = (lane >> 3);
    const int gkblk = (lane & 7) ^ (lane >> 3);   // XOR swizzle
    const int wr = wave >> 1, wc = wave & 1;
    const int mbase = wr * 64 + (lane & 15);
    const int nbase = wc * 64 + (lane & 15);
    const int quad  = lane >> 4;
    const int swz   = lane & 7;

    f32x4 acc[4][4] = {};

    for (int k0 = 0; k0 < K; k0 += 64) {
        #pragma unroll
        for (int r = 0; r < 4; ++r) {
            int c2 = r * 4 + wave;
            int row = c2 * 8 + srow;
            const __hip_bfloat16* ga = A + (bm + row) * lda + k0 + gkblk * 8;
            GL2LDS(ga, As + (size_t)c2 * 512);
            const __hip_bfloat16* gb = B + (bn + row) * ldb + k0 + gkblk * 8;
            GL2LDS(gb, Bs + (size_t)c2 * 512);
        }
        __syncthreads();
        #pragma unroll
        for (int kk = 0; kk < 2; ++kk) {
            int kblk = kk * 4 + quad;
            int p = (kblk ^ swz) * 8;
            short8 af[4], bf[4];
            #pragma unroll
            for (int mi = 0; mi < 4; ++mi)
                af[mi] = *reinterpret_cast<const short8*>(&As[(mbase + mi * 16) * 64 + p]);
            #pragma unroll
            for (int ni = 0; ni < 4; ++ni)
                bf[ni] = *reinterpret_cast<const short8*>(&Bs[(nbase + ni * 16) * 64 + p]);
            #pragma unroll
            for (int mi = 0; mi < 4; ++mi)
                #pragma unroll
                for (int ni = 0; ni < 4; ++ni)
                    acc[mi][ni] = __builtin_amdgcn_mfma_f32_16x16x32_bf16(
                        af[mi], bf[ni], acc[mi][ni], 0, 0, 0);
        }
        __syncthreads();
    }

    #pragma unroll
    for (int ni = 0; ni < 4; ++ni) {
        int gn = (int)bn + wc * 64 + ni * 16 + (lane & 15);
        float bv = (flags & 1) ? bias[gn] : 0.f;
        #pragma unroll
        for (int mi = 0; mi < 4; ++mi) {
            #pragma unroll
            for (int r = 0; r < 4; ++r) {
                size_t gm = bm + wr * 64 + mi * 16 + quad * 4 + r;
                float v = acc[mi][ni][r] + bv;
                size_t o = gm * ldc + gn;
                if (flags & 4) v += C[o];
                C[o] = v;
            }
        }
    }
}

// ---------------- generic fp32 GEMM: flags 1=bias,2=softplus,4=residual ------------
#define BM 64
#define BN 64
#define BK 16
__global__ __launch_bounds__(256) void gemm_f32(
    const float* __restrict__ A, const float* __restrict__ B,
    const float* __restrict__ bias, float* __restrict__ C,
    int M, int N, int K, int lda, int ldb, int ldc, int flags)
{
    __shared__ __align__(16) float As[BK][BM + 4];
    __shared__ __align__(16) float Bs[BK][BN];
    const int tid = threadIdx.x;
    const int bm = blockIdx.x * BM;
    const int bn = blockIdx.y * BN;
    const int tx = tid & 15;
    const int ty = tid >> 4;
    float acc[4][4] = {};
    for (int k0 = 0; k0 < K; k0 += BK) {
        #pragma unroll
        for (int i = 0; i < 4; ++i) {
            int l = tid + 256 * i;
            int m = l >> 4, kk = l & 15;
            int gm = bm + m, gk = k0 + kk;
            As[kk][m] = (gm < M && gk < K) ? A[(size_t)gm * lda + gk] : 0.f;
        }
        #pragma unroll
        for (int i = 0; i < 4; ++i) {
            int l = tid + 256 * i;
            int kk = l >> 6, n = l & 63;
            int gk = k0 + kk, gn = bn + n;
            Bs[kk][n] = (gk < K && gn < N) ? B[(size_t)gk * ldb + gn] : 0.f;
        }
        __syncthreads();
        #pragma unroll
        for (int kk = 0; kk < BK; ++kk) {
            float4 av = *(const float4*)&As[kk][ty * 4];
            float4 bv = *(const float4*)&Bs[kk][tx * 4];
            float a[4] = {av.x, av.y, av.z, av.w};
            float b[4] = {bv.x, bv.y, bv.z, bv.w};
            #pragma unroll
            for (int i = 0; i < 4; ++i)
                #pragma unroll
                for (int j = 0; j < 4; ++j)
                    acc[i][j] = fmaf(a[i], b[j], acc[i][j]);
        }
        __syncthreads();
    }
    #pragma unroll
    for (int i = 0; i < 4; ++i) {
        int gm = bm + ty * 4 + i;
        if (gm >= M) continue;
        #pragma unroll
        for (int j = 0; j < 4; ++j) {
            int gn = bn + tx * 4 + j;
            if (gn >= N) continue;
            float v = acc[i][j];
            if (flags & 1) v += bias[gn];
            if (flags & 2) v = (v > 20.f) ? v : log1pf(__expf(v));
            size_t o = (size_t)gm * ldc + gn;
            if (flags & 4) v += C[o];
            C[o] = v;
        }
    }
}

// ---------------- split-K fp32 GEMM ------------------------------------------------
__global__ __launch_bounds__(256) void gemm_f32_splitk(
    const float* __restrict__ A, const float* __restrict__ B,
    const float* __restrict__ bias, float* __restrict__ C,
    int M, int N, int K, int lda, int ldb, int ldc, int flags, int klen)
{
    __shared__ __align__(16) float As[BK][BM + 4];
    __shared__ __align__(16) float Bs[BK][BN];
    const int tid = threadIdx.x;
    const int bm = blockIdx.x * BM;
    const int bn = blockIdx.y * BN;
    const int kbeg = blockIdx.z * klen;
    const int kend = min(K, kbeg + klen);
    const int tx = tid & 15;
    const int ty = tid >> 4;
    float acc[4][4] = {};
    for (int k0 = kbeg; k0 < kend; k0 += BK) {
        #pragma unroll
        for (int i = 0; i < 4; ++i) {
            int l = tid + 256 * i;
            int m = l >> 4, kk = l & 15;
            int gm = bm + m, gk = k0 + kk;
            As[kk][m] = (gm < M && gk < K) ? A[(size_t)gm * lda + gk] : 0.f;
        }
        #pragma unroll
        for (int i = 0; i < 4; ++i) {
            int l = tid + 256 * i;
            int kk = l >> 6, n = l & 63;
            int gk = k0 + kk, gn = bn + n;
            Bs[kk][n] = (gk < K && gn < N) ? B[(size_t)gk * ldb + gn] : 0.f;
        }
        __syncthreads();
        #pragma unroll
        for (int kk = 0; kk < BK; ++kk) {
            float4 av = *(const float4*)&As[kk][ty * 4];
            float4 bv = *(const float4*)&Bs[kk][tx * 4];
            float a[4] = {av.x, av.y, av.z, av.w};
            float b[4] = {bv.x, bv.y, bv.z, bv.w};
            #pragma unroll
            for (int i = 0; i < 4; ++i)
                #pragma unroll
                for (int j = 0; j < 4; ++j)
                    acc[i][j] = fmaf(a[i], b[j], acc[i][j]);
        }
        __syncthreads();
    }
    #pragma unroll
    for (int i = 0; i < 4; ++i) {
        int gm = bm + ty * 4 + i;
        if (gm >= M) continue;
        #pragma unroll
        for (int j = 0; j < 4; ++j) {
            int gn = bn + tx * 4 + j;
            if (gn >= N) continue;
            float v = acc[i][j];
            if ((flags & 1) && blockIdx.z == 0) v += bias[gn];
            atomicAdd(&C[(size_t)gm * ldc + gn], v);
        }
    }
}

__global__ __launch_bounds__(256) void zero_k(float* __restrict__ p, int n)
{
    int idx = blockIdx.x * 256 + threadIdx.x;
    if (idx < n) p[idx] = 0.f;
}

// ---------------- rmsnorm over 512; flags: 1 = silu, 2 = bf16 output ----------------
__global__ __launch_bounds__(256) void rmsnorm_k(
    const float* __restrict__ in, const float* __restrict__ w,
    void* __restrict__ outp, int flags)
{
    int row = blockIdx.x;
    int tid = threadIdx.x;
    const float* ip = in + (size_t)row * D_MODEL;
    float v0 = ip[tid], v1 = ip[tid + 256];
    float ss = v0 * v0 + v1 * v1;
    #pragma unroll
    for (int off = 32; off >= 1; off >>= 1) ss += __shfl_xor(ss, off, 64);
    __shared__ float red[4];
    if ((tid & 63) == 0) red[tid >> 6] = ss;
    __syncthreads();
    float tot = red[0] + red[1] + red[2] + red[3];
    float sc = rsqrtf(tot * (1.f / D_MODEL) + 1e-6f);
    float o0 = v0 * sc * w[tid];
    float o1 = v1 * sc * w[tid + 256];
    if (flags & 1) { o0 = silu_f(o0); o1 = silu_f(o1); }
    if (flags & 2) {
        __hip_bfloat16* op = (__hip_bfloat16*)outp + (size_t)row * D_MODEL;
        op[tid] = __float2bfloat16(o0); op[tid + 256] = __float2bfloat16(o1);
    } else {
        float* op = (float*)outp + (size_t)row * D_MODEL;
        op[tid] = o0; op[tid + 256] = o1;
    }
}

// ---------------- causal depthwise conv (k=4) + bias + silu ----------------
__global__ __launch_bounds__(256) void conv_silu_k(
    const float* __restrict__ xz, const float* __restrict__ cw,
    const float* __restrict__ cb, float* __restrict__ xc)
{
    int idx = blockIdx.x * 256 + threadIdx.x;   // ROWS*D_INNER exact
    int d = idx & (D_INNER - 1);
    int row = idx >> 10;
    int t = row & (TT - 1);
    float4 w = *(const float4*)(cw + (size_t)d * 4);
    float acc = cb[d];
    if (t >= 3) {
        const float* base = xz + (size_t)(row - 3) * (2 * D_INNER) + d;
        acc = fmaf(base[0],    w.x, acc);
        acc = fmaf(base[2048], w.y, acc);
        acc = fmaf(base[4096], w.z, acc);
        acc = fmaf(base[6144], w.w, acc);
    } else {
        float wv[4] = {w.x, w.y, w.z, w.w};
        int bstart = row - t;
        #pragma unroll
        for (int j = 0; j < 4; ++j) {
            int ts = t + j - 3;
            if (ts >= 0) acc = fmaf(xz[(size_t)(bstart + ts) * (2 * D_INNER) + d], wv[j], acc);
        }
    }
    xc[idx] = silu_f(acc);
}

// ============ chunked selective scan, half-state-per-lane ============
// Lane layout (per wave): d_local = wave*32 + (lane&31), s-half = lane>>5 (8 states).
// Block 256 threads = 128 channels. grid (D_INNER/128, NCH, BB).
// B/C rows for the 64-step chunk staged in LDS (8 KB), broadcast reads.
__global__ __launch_bounds__(256) void scan_pass1_k(
    const float* __restrict__ dt, const float* __restrict__ xc,
    const float* __restrict__ xdbl, const float* __restrict__ A_log,
    float* __restrict__ hf, float* __restrict__ pf)
{
    __shared__ float BC[CHL][32];       // [t][B0..15, C0..15]
    const int tid = threadIdx.x;
    const int lane = tid & 63, wv = tid >> 6;
    const int d  = blockIdx.x * 128 + wv * 32 + (lane & 31);
    const int sh = (lane >> 5) * 8;
    const int c = blockIdx.y, b = blockIdx.z;
    const int row0 = b * TT + c * CHL;

    for (int i = tid; i < CHL * 8; i += 256) {
        int r = i >> 3, seg = i & 7;
        ((float4*)&BC[r][0])[seg] = ((const float4*)(xdbl + (size_t)(row0 + r) * 64 + 32))[seg];
    }
    __syncthreads();

    float Av[8], h[8], P[8];
    #pragma unroll
    for (int j = 0; j < 8; ++j) {
        Av[j] = -__expf(A_log[d * 16 + sh + j]);
        h[j] = 0.f; P[j] = 1.f;
    }
    float dtv = dt[(size_t)row0 * 2048 + d];
    float xv  = xc[(size_t)row0 * 1024 + d];
    for (int t = 0; t < CHL; ++t) {
        int rn = row0 + min(t + 1, CHL - 1);
        float dtn = dt[(size_t)rn * 2048 + d];
        float xvn = xc[(size_t)rn * 1024 + d];
        float dx = dtv * xv;
        #pragma unroll
        for (int j = 0; j < 8; ++j) {
            float dA = __expf(dtv * Av[j]);
            h[j] = fmaf(dA, h[j], dx * BC[t][sh + j]);
            P[j] *= dA;
        }
        dtv = dtn; xv = xvn;
    }
    size_t o = ((((size_t)b * NCH + c) * D_INNER) + d) * 16 + sh;
    #pragma unroll
    for (int j = 0; j < 8; ++j) { hf[o + j] = h[j]; pf[o + j] = P[j]; }
}

__global__ __launch_bounds__(256) void scan_combine_k(
    const float* __restrict__ hf, const float* __restrict__ pf,
    float* __restrict__ hin)
{
    int idx = blockIdx.x * 256 + threadIdx.x;   // BB*D_INNER*16 exact
    int b = idx >> 14;
    int rest = idx & 16383;
    float h = 0.f;
    for (int c = 0; c < NCH; ++c) {
        size_t o = (((size_t)b * NCH + c) * (D_INNER * 16)) + rest;
        hin[o] = h;
        h = fmaf(pf[o], h, hf[o]);
    }
}

__global__ __launch_bounds__(256) void scan_pass2_k(
    const float* __restrict__ dt, const float* __restrict__ xc,
    const float* __restrict__ xdbl, const float* __restrict__ A_log,
    const float* __restrict__ Dp, const float* __restrict__ hin,
    float* __restrict__ y)   // y written at row*2048+d (overwrites dt slot, safe in-order)
{
    __shared__ float BC[CHL][32];
    const int tid = threadIdx.x;
    const int lane = tid & 63, wv = tid >> 6;
    const int d  = blockIdx.x * 128 + wv * 32 + (lane & 31);
    const int sh = (lane >> 5) * 8;
    const int c = blockIdx.y, b = blockIdx.z;
    const int row0 = b * TT + c * CHL;

    for (int i = tid; i < CHL * 8; i += 256) {
        int r = i >> 3, seg = i & 7;
        ((float4*)&BC[r][0])[seg] = ((const float4*)(xdbl + (size_t)(row0 + r) * 64 + 32))[seg];
    }
    __syncthreads();

    float Av[8], h[8];
    size_t o = ((((size_t)b * NCH + c) * D_INNER) + d) * 16 + sh;
    #pragma unroll
    for (int j = 0; j < 8; ++j) {
        Av[j] = -__expf(A_log[d * 16 + sh + j]);
        h[j] = hin[o + j];
    }
    const float Dv = Dp[d];
    float dtv = dt[(size_t)row0 * 2048 + d];
    float xv  = xc[(size_t)row0 * 1024 + d];
    for (int t = 0; t < CHL; ++t) {
        int rn = row0 + min(t + 1, CHL - 1);
        float dtn = dt[(size_t)rn * 2048 + d];
        float xvn = xc[(size_t)rn * 1024 + d];
        float dx = dtv * xv;
        float acc = 0.f;
        #pragma unroll
        for (int j = 0; j < 8; ++j) {
            float dA = __expf(dtv * Av[j]);
            h[j] = fmaf(dA, h[j], dx * BC[t][sh + j]);
            acc = fmaf(h[j], BC[t][16 + sh + j], acc);
        }
        acc += __shfl_xor(acc, 32);
        if (sh == 0) y[(size_t)(row0 + t) * 2048 + d] = fmaf(xv, Dv, acc);
        dtv = dtn; xv = xvn;
    }
}

// ---------------- u = y * silu(z) -> bf16 ----------------
__global__ __launch_bounds__(256) void ymulz_k(
    const float* __restrict__ xz, __hip_bfloat16* __restrict__ u)
{
    int idx = blockIdx.x * 256 + threadIdx.x;   // ROWS*D_INNER exact
    int d = idx & (D_INNER - 1);
    size_t row = (size_t)(idx >> 10);
    float yv = xz[row * (2 * D_INNER) + d];
    float zv = xz[row * (2 * D_INNER) + D_INNER + d];
    u[idx] = __float2bfloat16(yv * silu_f(zv));
}

__global__ __launch_bounds__(256) void copy_k(const float* __restrict__ src, float* __restrict__ dst, int n)
{
    int idx = blockIdx.x * 256 + threadIdx.x;
    if (idx < n) dst[idx] = src[idx];
}

extern "C" void kernel_launch(void* const* d_in, const int* in_sizes, int n_in,
                              void* d_out, int out_size, void* d_ws, size_t ws_size,
                              hipStream_t stream)
{
    const float* state   = (const float*)d_in[0];
    const float* pact    = (const float*)d_in[1];
    const float* W_state = (const float*)d_in[2];
    const float* b_state = (const float*)d_in[3];
    const float* W_act   = (const float*)d_in[4];
    const float* b_act   = (const float*)d_in[5];
    const float* W_fuse  = (const float*)d_in[6];
    const float* b_fuse  = (const float*)d_in[7];
    const float* g_fuse  = (const float*)d_in[8];
    const float* norm_w  = (const float*)d_in[9];
    const float* W_in    = (const float*)d_in[10];
    const float* conv_w  = (const float*)d_in[11];
    const float* conv_b  = (const float*)d_in[12];
    const float* W_x     = (const float*)d_in[13];
    const float* W_dt    = (const float*)d_in[14];
    const float* b_dt    = (const float*)d_in[15];
    const float* A_log   = (const float*)d_in[16];
    const float* Dp      = (const float*)d_in[17];
    const float* W_out   = (const float*)d_in[18];
    const float* W_head  = (const float*)d_in[19];
    const float* b_head  = (const float*)d_in[20];

    float* ws = (float*)d_ws;
    float* X    = ws;                     // 8192*512 fp32
    float* R1   = ws + 4194304;           // EMB_BF / XNORM_BF / HIN
    float* XZ   = ws + 6815744;           // 8192*2048 fp32 (dt aliased in lower half)
    float* XC   = ws + 23592960;          // 8192*1024 fp32
    float* R2   = ws + 31981568;          // HF+PF / U_BF
    float* XDBL = ws + 36175872;          // 8192*64 fp32
    float* WT_f = ws + 36700160;          // transposed bf16 weights
    // end: 40,009,728 floats = 160 MB

    __hip_bfloat16* EMB_BF   = (__hip_bfloat16*)R1;
    __hip_bfloat16* XNORM_BF = (__hip_bfloat16*)R1;
    float*          HIN      = R1;
    float*          HF       = R2;
    float*          PF       = R2 + 2097152;
    __hip_bfloat16* U_BF     = (__hip_bfloat16*)R2;
    __hip_bfloat16* WT       = (__hip_bfloat16*)WT_f;
    __hip_bfloat16* WfuseT   = WT;                          // 640*512
    __hip_bfloat16* WinT     = WT + 327680;                 // 4 * 2048*512
    __hip_bfloat16* WoutT    = WT + 4521984;                // 4 * 512*1024

    dim3 b256(256);

    transcast_k<<<dim3(8, 10, 1),  b256, 0, stream>>>(W_fuse, WfuseT, FUSE_IN, D_MODEL);
    transcast_k<<<dim3(32, 8, 4),  b256, 0, stream>>>(W_in,   WinT,   D_MODEL, 2 * D_INNER);
    transcast_k<<<dim3(8, 16, 4),  b256, 0, stream>>>(W_out,  WoutT,  D_INNER, D_MODEL);

    embed_k<<<ROWS * FUSE_IN / 256, b256, 0, stream>>>(state, pact, W_state, b_state, W_act, b_act, EMB_BF);
    gemm_bf16<<<dim3(64, 4), b256, 0, stream>>>(EMB_BF, WfuseT, b_fuse, X,
        ROWS, D_MODEL, FUSE_IN, FUSE_IN, FUSE_IN, D_MODEL, 1);
    rmsnorm_k<<<ROWS, b256, 0, stream>>>(X, g_fuse, X, 1);

    for (int L = 0; L < N_LAYERS; ++L) {
        const float* cw  = conv_w + (size_t)L * D_INNER * 4;
        const float* cb  = conv_b + (size_t)L * D_INNER;
        const float* Wx  = W_x   + (size_t)L * D_INNER * 64;
        const float* Wd  = W_dt  + (size_t)L * DT_RANK * D_INNER;
        const float* bd  = b_dt  + (size_t)L * D_INNER;
        const float* Al  = A_log + (size_t)L * D_INNER * D_STATE;
        const float* Dpl = Dp    + (size_t)L * D_INNER;
        __hip_bfloat16* WiT = WinT  + (size_t)L * 2 * D_INNER * D_MODEL;
        __hip_bfloat16* WoT = WoutT + (size_t)L * D_MODEL * D_INNER;

        rmsnorm_k<<<ROWS, b256, 0, stream>>>(X, norm_w + L * D_MODEL, XNORM_BF, 2);
        gemm_bf16<<<dim3(64, 16), b256, 0, stream>>>(XNORM_BF, WiT, nullptr, XZ,
            ROWS, 2 * D_INNER, D_MODEL, D_MODEL, D_MODEL, 2 * D_INNER, 0);
        conv_silu_k<<<ROWS * D_INNER / 256, b256, 0, stream>>>(XZ, cw, cb, XC);
        zero_k<<<ROWS * 64 / 256, b256, 0, stream>>>(XDBL, ROWS * 64);
        gemm_f32_splitk<<<dim3(128, 1, 8), b256, 0, stream>>>(XC, Wx, nullptr, XDBL,
            ROWS, 64, D_INNER, D_INNER, 64, 64, 0, 128);
        gemm_f32<<<dim3(128, 16), b256, 0, stream>>>(XDBL, Wd, bd, XZ,
            ROWS, D_INNER, DT_RANK, 64, D_INNER, 2 * D_INNER, 3);   // dt -> XZ lower half
        scan_pass1_k<<<dim3(8, NCH, BB), b256, 0, stream>>>(XZ, XC, XDBL, Al, HF, PF);
        scan_combine_k<<<BB * D_INNER * 16 / 256, b256, 0, stream>>>(HF, PF, HIN);
        scan_pass2_k<<<dim3(8, NCH, BB), b256, 0, stream>>>(XZ, XC, XDBL, Al, Dpl, HIN, XZ);
        ymulz_k<<<ROWS * D_INNER / 256, b256, 0, stream>>>(XZ, U_BF);
        gemm_bf16<<<dim3(64, 4), b256, 0, stream>>>(U_BF, WoT, nullptr, X,
            ROWS, D_MODEL, D_INNER, D_INNER, D_INNER, D_MODEL, 4);
    }

    zero_k<<<ROWS * TGT_DIM / 256, b256, 0, stream>>>((float*)d_out, ROWS * TGT_DIM);
    gemm_f32_splitk<<<dim3(128, 1, 8), b256, 0, stream>>>(X, W_head, b_head, (float*)d_out,
        ROWS, TGT_DIM, D_MODEL, D_MODEL, TGT_DIM, TGT_DIM, 1, 64);
    copy_k<<<ROWS * D_MODEL / 256, b256, 0, stream>>>(X, (float*)d_out + ROWS * TGT_DIM, ROWS * D_MODEL);
}